// Round 13
// baseline (356.303 us; speedup 1.0000x reference)
//
#include <hip/hip_runtime.h>
#include <hip/hip_bf16.h>

#define VOCAB 50000
#define EMBD  512
#define HID   1024
#define NB    256
#define SEQW  26
#define MTOT  (SEQW * NB)   /* 6656 */
#define NGATE (4 * HID)     /* 4096 */

typedef short short8 __attribute__((ext_vector_type(8)));
typedef _Float16 half8 __attribute__((ext_vector_type(8)));
typedef float f32x4  __attribute__((ext_vector_type(4)));
typedef float f32x2  __attribute__((ext_vector_type(2)));

__device__ __forceinline__ unsigned short f16bits(_Float16 h) {
    union { _Float16 h; unsigned short u; } cv; cv.h = h; return cv.u;
}

__device__ __forceinline__ void gload16(const void* g, void* l) {
    __builtin_amdgcn_global_load_lds(
        (const __attribute__((address_space(1))) void*)g,
        (__attribute__((address_space(3))) void*)l, 16, 0, 0);
}

// ---------------- init: zero h slot0 + barrier state ----------------
__global__ void init_kernel(unsigned short* __restrict__ hBuf,
                            unsigned int* __restrict__ bar) {
    int idx = blockIdx.x * blockDim.x + threadIdx.x;  // 1024 x 256
    hBuf[idx] = 0;                                     // slot 0 = h_0 = 0
    if (idx < 4096) bar[idx] = 0;
}

// ---------------- Wemb transpose: [512][50000] f32 -> WembT [50000][512] f16
__global__ void transp_kernel(const float* __restrict__ W,
                              unsigned short* __restrict__ WT) {
    __shared__ _Float16 tile[64][72];
    int v0 = blockIdx.x * 64;
    int e0 = blockIdx.y * 64;
    int tid = threadIdx.x;

    int e_loc = tid >> 2, q = tid & 3;
    int vq = q * 16;
    if (v0 + vq < VOCAB) {
        const float* src = W + (size_t)(e0 + e_loc) * VOCAB + v0 + vq;
        #pragma unroll
        for (int j = 0; j < 4; ++j) {
            f32x4 x = *(const f32x4*)(src + 4 * j);
            #pragma unroll
            for (int i = 0; i < 4; ++i)
                tile[vq + 4 * j + i][e_loc] = (_Float16)x[i];
        }
    }
    __syncthreads();

    int v_loc = tid >> 2;
    int ec = q * 16;
    int v = v0 + v_loc;
    if (v < VOCAB) {
        short8* dst = (short8*)(WT + (size_t)v * EMBD + e0 + ec);
        dst[0] = *(const short8*)&tile[v_loc][ec];
        dst[1] = *(const short8*)&tile[v_loc][ec + 8];
    }
}

// ---------------- embedding: row-gather from WembT + tanh -> fp16 -----------
__global__ void embed_kernel(const int* __restrict__ qv,
                             const unsigned short* __restrict__ WT,
                             unsigned short* __restrict__ eHi) {
    int pair = blockIdx.x * 4 + (threadIdx.x >> 6);
    int t = pair >> 8, b = pair & 255;
    int lane = threadIdx.x & 63;
    int tok = qv[b * SEQW + t];
    short8 out = {};
    if (tok > 0) {
        short8 v = *(const short8*)(WT + (size_t)(tok - 1) * EMBD + lane * 8);
        #pragma unroll
        for (int i = 0; i < 8; ++i) {
            union { short s; _Float16 h; } cv; cv.s = v[i];
            out[i] = (short)f16bits((_Float16)tanhf((float)cv.h));
        }
    }
    *(short8*)(eHi + (size_t)pair * EMBD + lane * 8) = out;
}

// ---------------- weight conversion: ih fp16, hh fp16, bsum -----------------
__global__ void convw_kernel(const float* __restrict__ Wih,
                             const float* __restrict__ Whh,
                             const float* __restrict__ b_ih,
                             const float* __restrict__ b_hh,
                             unsigned short* __restrict__ ih,
                             unsigned short* __restrict__ hh,
                             float* __restrict__ bsum) {
    int j = blockIdx.x; // 0..4095
    if (threadIdx.x == 0) bsum[j] = b_ih[j] + b_hh[j];
    for (int col = threadIdx.x; col < EMBD; col += blockDim.x)
        ih[(size_t)j * EMBD + col] = f16bits((_Float16)Wih[(size_t)j * EMBD + col]);
    for (int col = threadIdx.x; col < HID; col += blockDim.x)
        hh[(size_t)j * HID + col] = f16bits((_Float16)Whh[(size_t)j * HID + col]);
}

// ---------------- pre-GEMM v2: LDS-staged (m97-style), fp16 1-term ----------
__global__ __launch_bounds__(512, 2) void pregemm_kernel(
    const unsigned short* __restrict__ eHi,
    const unsigned short* __restrict__ ih,
    const float* __restrict__ bsum,
    float* __restrict__ G0n)
{
    __shared__ char smem[65536];   // A dbuf [2][16KB] @0, B dbuf [2][16KB] @32768

    int id = blockIdx.x;
    int xcd = id & 7, lid = id >> 3;
    int pc = xcd * 4 + (lid & 3);   // 0..31
    int pm = lid >> 2;              // 0..51
    int m0 = pm * 128;

    int tid = threadIdx.x;
    int w = tid >> 6;               // 0..7
    int mh = w >> 2, nh = w & 3;
    int lane = tid & 63;
    int col16 = lane & 15, g4 = lane >> 4;

    int sr = lane >> 3, sc = lane & 7;
    int ra0 = w * 16 + sr, ra1 = ra0 + 8;
    const char* eB = (const char*)eHi;
    const char* iB = (const char*)ih;
    size_t aOffG0 = (size_t)(m0 + ra0) * 1024 + (size_t)(((sc ^ (ra0 & 7))) * 16);
    size_t aOffG1 = (size_t)(m0 + ra1) * 1024 + (size_t)(((sc ^ (ra1 & 7))) * 16);
    int gb0 = (ra0 >> 5) * 1024 + pc * 32 + (ra0 & 31);
    int gb1 = (ra1 >> 5) * 1024 + pc * 32 + (ra1 & 31);
    size_t bOffG0 = (size_t)gb0 * 1024 + (size_t)(((sc ^ (ra0 & 7))) * 16);
    size_t bOffG1 = (size_t)gb1 * 1024 + (size_t)(((sc ^ (ra1 & 7))) * 16);
    int ldsRow0 = (w * 16) * 128;
    int ldsRow1 = (w * 16 + 8) * 128;

    f32x4 acc[4][2];
    #pragma unroll
    for (int fm = 0; fm < 4; ++fm)
        #pragma unroll
        for (int fn = 0; fn < 2; ++fn)
            acc[fm][fn] = (f32x4){0.f, 0.f, 0.f, 0.f};

    int swb = col16 & 7;
    int aRow[4], bRow[2];
    #pragma unroll
    for (int fm = 0; fm < 4; ++fm) aRow[fm] = (mh * 64 + fm * 16 + col16) * 128;
    #pragma unroll
    for (int fn = 0; fn < 2; ++fn) bRow[fn] = (nh * 32 + fn * 16 + col16) * 128;

#define STAGE(kb, buf) do { \
        int kby = (kb) * 128; \
        char* aD = smem + (buf) * 16384; \
        char* bD = smem + 32768 + (buf) * 16384; \
        gload16(eB + aOffG0 + kby, aD + ldsRow0); \
        gload16(eB + aOffG1 + kby, aD + ldsRow1); \
        gload16(iB + bOffG0 + kby, bD + ldsRow0); \
        gload16(iB + bOffG1 + kby, bD + ldsRow1); \
    } while (0)

    STAGE(0, 0);
    #pragma unroll
    for (int kb = 0; kb < 8; ++kb) {
        int cur = kb & 1;
        __syncthreads();
        if (kb < 7) STAGE(kb + 1, cur ^ 1);
        const char* aS = smem + cur * 16384;
        const char* bS = smem + 32768 + cur * 16384;
        #pragma unroll
        for (int kk = 0; kk < 2; ++kk) {
            int co = ((kk * 4 + g4) ^ swb) * 16;
            half8 bF[2];
            #pragma unroll
            for (int fn = 0; fn < 2; ++fn)
                bF[fn] = *(const half8*)(const void*)(bS + bRow[fn] + co);
            #pragma unroll
            for (int fm = 0; fm < 4; ++fm) {
                half8 aF = *(const half8*)(const void*)(aS + aRow[fm] + co);
                #pragma unroll
                for (int fn = 0; fn < 2; ++fn)
                    acc[fm][fn] = __builtin_amdgcn_mfma_f32_16x16x32_f16(
                        aF, bF[fn], acc[fm][fn], 0, 0, 0);
            }
        }
    }
#undef STAGE

    #pragma unroll
    for (int fn = 0; fn < 2; ++fn) {
        int cp = nh * 32 + fn * 16 + col16;
        int gate = cp >> 5;
        int jh = pc * 32 + (cp & 31);
        int ct = jh >> 4, jl = jh & 15;
        int cidx = gate * 16 + jl;
        float bv = bsum[gate * HID + jh];
        #pragma unroll
        for (int fm = 0; fm < 4; ++fm)
            #pragma unroll
            for (int r = 0; r < 4; ++r) {
                int row = m0 + mh * 64 + fm * 16 + g4 * 4 + r;
                int t = row >> 8, b = row & 255;
                G0n[(((size_t)t * 64 + ct) * 256 + b) * 64 + cidx] =
                    acc[fm][fn][r] + bv;
            }
    }
}

// ---------------- persistent LSTM: B in regs, A in LDS, multi-ctr barrier ---
// R13 deltas vs R12 (isolated): (1) barrier arrival split over 8 sub-counters
// per group (8 blocks each, 64B apart) and tid0 polls all 8 (no root/gen) —
// cuts 64-way RMW serialization; (2) next-step G0 loads issued BEFORE the
// h-store/drain so their L3 latency completes under the barrier spin.
__global__ __launch_bounds__(512, 2) void lstm_persist(
    const unsigned short* __restrict__ hh,     // fp16 Whh [4096][1024]
    unsigned short* __restrict__ hBuf,         // 27 slots of NB*HID fp16
    const float* __restrict__ G0n,
    float* __restrict__ out,
    unsigned int* __restrict__ bar)
{
    extern __shared__ char smem[];
    float* gbuf = (float*)(smem + 131072);

    int bx = blockIdx.x;
    int grp = (bx & 7) >> 1;                     // 0..3
    int ct  = ((bx >> 3) & 31) + 32 * (bx & 1);  // 0..63
    int m0  = grp * 64;
    int jh0 = ct * 16;

    int tid = threadIdx.x;
    int w = tid >> 6;
    int gate = w & 3, mh = w >> 2;
    int lane = tid & 63;
    int col16 = lane & 15, g4 = lane >> 4;

    // barrier: 8 sub-counters per group, 16 uints (64B) apart
    unsigned int* subBase = bar + grp * 128;
    unsigned int* mySub = subBase + (ct >> 3) * 16;

    // ---- preload B (this wave's 16 Whh gate-rows) into registers ----
    half8 bB[32];
    {
        const char* bRow = (const char*)hh +
            ((size_t)(gate * HID + jh0 + col16) * HID + g4 * 8) * 2;
        #pragma unroll
        for (int kk = 0; kk < 32; ++kk)
            bB[kk] = *(const half8*)(const void*)(bRow + kk * 64);
    }

    int ml = tid >> 3, jl2 = (tid & 7) * 2;
    float cReg[2] = {0.f, 0.f};

    // G0 prefetch for t=0
    f32x2 g0v[4];
    {
        const float* pg = G0n + (((size_t)ct) * 256 + (m0 + ml)) * 64 + jl2;
        #pragma unroll
        for (int q = 0; q < 4; ++q) g0v[q] = *(const f32x2*)(pg + q * 16);
    }

    for (int t = 0; t < SEQW; ++t) {
        const unsigned short* hIn = hBuf + (size_t)t * NB * HID;
        unsigned short* hOut = hBuf + (size_t)(t + 1) * NB * HID;

        f32x4 acc0 = {0.f, 0.f, 0.f, 0.f};
        f32x4 acc1 = {0.f, 0.f, 0.f, 0.f};

        if (t > 0) {
            {
                const char* hRowB = (const char*)hIn +
                    (size_t)(m0 + lane) * (HID * 2) + w * 256;
                #pragma unroll
                for (int j = 0; j < 4; ++j) {
                    int kk = w * 4 + j;
                    short8 v[4];
                    #pragma unroll
                    for (int q = 0; q < 4; ++q)
                        v[q] = *(const short8*)(const void*)(hRowB + j * 64 + q * 16);
                    #pragma unroll
                    for (int q = 0; q < 4; ++q)
                        *(short8*)(smem + ((kk * 4 + q) * 64 + lane) * 16) = v[q];
                }
            }
            __syncthreads();

            #pragma unroll
            for (int kk = 0; kk < 32; ++kk) {
                const char* slab = smem + (kk * 4 + g4) * 1024;
                half8 a0 = *(const half8*)(const void*)(slab + (mh * 32 + col16) * 16);
                half8 a1 = *(const half8*)(const void*)(slab + (mh * 32 + 16 + col16) * 16);
                acc0 = __builtin_amdgcn_mfma_f32_16x16x32_f16(a0, bB[kk], acc0, 0, 0, 0);
                acc1 = __builtin_amdgcn_mfma_f32_16x16x32_f16(a1, bB[kk], acc1, 0, 0, 0);
            }
        }

        #pragma unroll
        for (int r = 0; r < 4; ++r) {
            gbuf[(gate * 64 + mh * 32 + g4 * 4 + r) * 20 + col16] = acc0[r];
            gbuf[(gate * 64 + mh * 32 + 16 + g4 * 4 + r) * 20 + col16] = acc1[r];
        }
        __syncthreads();

        f32x2 gv[4];
        #pragma unroll
        for (int q = 0; q < 4; ++q)
            gv[q] = *(const f32x2*)&gbuf[(q * 64 + ml) * 20 + jl2];

        float hN[2];
        #pragma unroll
        for (int u = 0; u < 2; ++u) {
            float gi  = gv[0][u] + g0v[0][u];
            float gf  = gv[1][u] + g0v[1][u];
            float gg_ = gv[2][u] + g0v[2][u];
            float go  = gv[3][u] + g0v[3][u];
            float si = 1.0f / (1.0f + expf(-gi));
            float sf = 1.0f / (1.0f + expf(-gf));
            float so = 1.0f / (1.0f + expf(-go));
            float tg = tanhf(gg_);
            float cN = sf * cReg[u] + si * tg;
            hN[u] = so * tanhf(cN);
            cReg[u] = cN;
        }
        size_t p = (size_t)(m0 + ml) * HID + jh0 + jl2;
        if (t == SEQW - 1) {
            *(f32x2*)(out + p) = (f32x2){hN[0], hN[1]};
        } else {
            // issue next-step G0 loads FIRST (h-independent): they drain
            // during the pre-arrival syncthreads + barrier spin
            f32x2 g0n[4];
            {
                const float* pg = G0n +
                    (((size_t)(t + 1) * 64 + ct) * 256 + (m0 + ml)) * 64 + jl2;
                #pragma unroll
                for (int q = 0; q < 4; ++q) g0n[q] = *(const f32x2*)(pg + q * 16);
            }

            unsigned int hv = (unsigned int)f16bits((_Float16)hN[0]) |
                              ((unsigned int)f16bits((_Float16)hN[1]) << 16);
            __hip_atomic_store((unsigned int*)(hOut + p), hv,
                               __ATOMIC_RELAXED, __HIP_MEMORY_SCOPE_AGENT);

            __syncthreads();   // drains vmcnt: h stores acked at L3, G0 in regs
            if (tid == 0) {
                unsigned int t1 = (unsigned int)(t + 1);
                unsigned int tgt = t1 * 8u;
                __hip_atomic_fetch_add(mySub, 1u, __ATOMIC_RELAXED,
                                       __HIP_MEMORY_SCOPE_AGENT);
                for (;;) {
                    bool ok = true;
                    #pragma unroll
                    for (int s = 0; s < 8; ++s)
                        ok &= (__hip_atomic_load(subBase + s * 16,
                                                 __ATOMIC_RELAXED,
                                                 __HIP_MEMORY_SCOPE_AGENT) >= tgt);
                    if (ok) break;
                    __builtin_amdgcn_s_sleep(1);
                }
            }
            __syncthreads();

            #pragma unroll
            for (int q = 0; q < 4; ++q) g0v[q] = g0n[q];
        }
    }
}

extern "C" void kernel_launch(void* const* d_in, const int* in_sizes, int n_in,
                              void* d_out, int out_size, void* d_ws, size_t ws_size,
                              hipStream_t stream) {
    const int*   qv   = (const int*)d_in[0];
    const float* Wemb = (const float*)d_in[2];
    const float* Wih  = (const float*)d_in[3];
    const float* Whh  = (const float*)d_in[4];
    const float* b_ih = (const float*)d_in[5];
    const float* b_hh = (const float*)d_in[6];
    float* out = (float*)d_out;

    char* ws = (char*)d_ws;
    size_t off = 0;
    unsigned short* eHi  = (unsigned short*)(ws + off); off += (size_t)MTOT * EMBD * 2;
    unsigned short* ih   = (unsigned short*)(ws + off); off += (size_t)NGATE * EMBD * 2;
    unsigned short* hh   = (unsigned short*)(ws + off); off += (size_t)NGATE * HID * 2;
    unsigned short* hBuf = (unsigned short*)(ws + off); off += (size_t)(SEQW + 1) * NB * HID * 2;
    float* bsum          = (float*)(ws + off);          off += (size_t)NGATE * 4;
    unsigned int* bar    = (unsigned int*)(ws + off);   off += 16384;
    off = (off + 255) & ~(size_t)255;
    float* G0n           = (float*)(ws + off);          off += (size_t)MTOT * NGATE * 4; // 109 MB
    unsigned short* WembT = (unsigned short*)G0n;       // aliases G0n (dead before pregemm)

    init_kernel<<<NB * HID / 256, 256, 0, stream>>>(hBuf, bar);
    transp_kernel<<<dim3(782, 8), 256, 0, stream>>>(Wemb, WembT);
    embed_kernel<<<MTOT / 4, 256, 0, stream>>>(qv, WembT, eHi);
    convw_kernel<<<NGATE, 256, 0, stream>>>(Wih, Whh, b_ih, b_hh, ih, hh, bsum);
    pregemm_kernel<<<1664, 512, 0, stream>>>(eHi, ih, bsum, G0n);

    lstm_persist<<<256, 512, 151552, stream>>>(hh, hBuf, G0n, out, bar);
}

// Round 14
// 280.591 us; speedup vs baseline: 1.2698x; 1.2698x over previous
//
#include <hip/hip_runtime.h>
#include <hip/hip_bf16.h>

#define VOCAB 50000
#define EMBD  512
#define HID   1024
#define NB    256
#define SEQW  26
#define MTOT  (SEQW * NB)   /* 6656 */
#define NGATE (4 * HID)     /* 4096 */

typedef short short8 __attribute__((ext_vector_type(8)));
typedef _Float16 half8 __attribute__((ext_vector_type(8)));
typedef float f32x4  __attribute__((ext_vector_type(4)));
typedef float f32x2  __attribute__((ext_vector_type(2)));

__device__ __forceinline__ unsigned short f16bits(_Float16 h) {
    union { _Float16 h; unsigned short u; } cv; cv.h = h; return cv.u;
}

__device__ __forceinline__ void gload16(const void* g, void* l) {
    __builtin_amdgcn_global_load_lds(
        (const __attribute__((address_space(1))) void*)g,
        (__attribute__((address_space(3))) void*)l, 16, 0, 0);
}

// ---------------- init: zero h slot0 + barrier flags ----------------
__global__ void init_kernel(unsigned short* __restrict__ hBuf,
                            unsigned int* __restrict__ bar) {
    int idx = blockIdx.x * blockDim.x + threadIdx.x;  // 1024 x 256
    hBuf[idx] = 0;                                     // slot 0 = h_0 = 0
    if (idx < 4096) bar[idx] = 0;
}

// ---------------- Wemb transpose: [512][50000] f32 -> WembT [50000][512] f16
__global__ void transp_kernel(const float* __restrict__ W,
                              unsigned short* __restrict__ WT) {
    __shared__ _Float16 tile[64][72];
    int v0 = blockIdx.x * 64;
    int e0 = blockIdx.y * 64;
    int tid = threadIdx.x;

    int e_loc = tid >> 2, q = tid & 3;
    int vq = q * 16;
    if (v0 + vq < VOCAB) {
        const float* src = W + (size_t)(e0 + e_loc) * VOCAB + v0 + vq;
        #pragma unroll
        for (int j = 0; j < 4; ++j) {
            f32x4 x = *(const f32x4*)(src + 4 * j);
            #pragma unroll
            for (int i = 0; i < 4; ++i)
                tile[vq + 4 * j + i][e_loc] = (_Float16)x[i];
        }
    }
    __syncthreads();

    int v_loc = tid >> 2;
    int ec = q * 16;
    int v = v0 + v_loc;
    if (v < VOCAB) {
        short8* dst = (short8*)(WT + (size_t)v * EMBD + e0 + ec);
        dst[0] = *(const short8*)&tile[v_loc][ec];
        dst[1] = *(const short8*)&tile[v_loc][ec + 8];
    }
}

// ---------------- embedding: row-gather from WembT + tanh -> fp16 -----------
__global__ void embed_kernel(const int* __restrict__ qv,
                             const unsigned short* __restrict__ WT,
                             unsigned short* __restrict__ eHi) {
    int pair = blockIdx.x * 4 + (threadIdx.x >> 6);
    int t = pair >> 8, b = pair & 255;
    int lane = threadIdx.x & 63;
    int tok = qv[b * SEQW + t];
    short8 out = {};
    if (tok > 0) {
        short8 v = *(const short8*)(WT + (size_t)(tok - 1) * EMBD + lane * 8);
        #pragma unroll
        for (int i = 0; i < 8; ++i) {
            union { short s; _Float16 h; } cv; cv.s = v[i];
            out[i] = (short)f16bits((_Float16)tanhf((float)cv.h));
        }
    }
    *(short8*)(eHi + (size_t)pair * EMBD + lane * 8) = out;
}

// ---------------- weight conversion: ih fp16, hh fp16, bsum -----------------
__global__ void convw_kernel(const float* __restrict__ Wih,
                             const float* __restrict__ Whh,
                             const float* __restrict__ b_ih,
                             const float* __restrict__ b_hh,
                             unsigned short* __restrict__ ih,
                             unsigned short* __restrict__ hh,
                             float* __restrict__ bsum) {
    int j = blockIdx.x; // 0..4095
    if (threadIdx.x == 0) bsum[j] = b_ih[j] + b_hh[j];
    for (int col = threadIdx.x; col < EMBD; col += blockDim.x)
        ih[(size_t)j * EMBD + col] = f16bits((_Float16)Wih[(size_t)j * EMBD + col]);
    for (int col = threadIdx.x; col < HID; col += blockDim.x)
        hh[(size_t)j * HID + col] = f16bits((_Float16)Whh[(size_t)j * HID + col]);
}

// ---------------- pre-GEMM v2: LDS-staged (m97-style), fp16 1-term ----------
__global__ __launch_bounds__(512, 2) void pregemm_kernel(
    const unsigned short* __restrict__ eHi,
    const unsigned short* __restrict__ ih,
    const float* __restrict__ bsum,
    float* __restrict__ G0n)
{
    __shared__ char smem[65536];   // A dbuf [2][16KB] @0, B dbuf [2][16KB] @32768

    int id = blockIdx.x;
    int xcd = id & 7, lid = id >> 3;
    int pc = xcd * 4 + (lid & 3);   // 0..31
    int pm = lid >> 2;              // 0..51
    int m0 = pm * 128;

    int tid = threadIdx.x;
    int w = tid >> 6;               // 0..7
    int mh = w >> 2, nh = w & 3;
    int lane = tid & 63;
    int col16 = lane & 15, g4 = lane >> 4;

    int sr = lane >> 3, sc = lane & 7;
    int ra0 = w * 16 + sr, ra1 = ra0 + 8;
    const char* eB = (const char*)eHi;
    const char* iB = (const char*)ih;
    size_t aOffG0 = (size_t)(m0 + ra0) * 1024 + (size_t)(((sc ^ (ra0 & 7))) * 16);
    size_t aOffG1 = (size_t)(m0 + ra1) * 1024 + (size_t)(((sc ^ (ra1 & 7))) * 16);
    int gb0 = (ra0 >> 5) * 1024 + pc * 32 + (ra0 & 31);
    int gb1 = (ra1 >> 5) * 1024 + pc * 32 + (ra1 & 31);
    size_t bOffG0 = (size_t)gb0 * 1024 + (size_t)(((sc ^ (ra0 & 7))) * 16);
    size_t bOffG1 = (size_t)gb1 * 1024 + (size_t)(((sc ^ (ra1 & 7))) * 16);
    int ldsRow0 = (w * 16) * 128;
    int ldsRow1 = (w * 16 + 8) * 128;

    f32x4 acc[4][2];
    #pragma unroll
    for (int fm = 0; fm < 4; ++fm)
        #pragma unroll
        for (int fn = 0; fn < 2; ++fn)
            acc[fm][fn] = (f32x4){0.f, 0.f, 0.f, 0.f};

    int swb = col16 & 7;
    int aRow[4], bRow[2];
    #pragma unroll
    for (int fm = 0; fm < 4; ++fm) aRow[fm] = (mh * 64 + fm * 16 + col16) * 128;
    #pragma unroll
    for (int fn = 0; fn < 2; ++fn) bRow[fn] = (nh * 32 + fn * 16 + col16) * 128;

#define STAGE(kb, buf) do { \
        int kby = (kb) * 128; \
        char* aD = smem + (buf) * 16384; \
        char* bD = smem + 32768 + (buf) * 16384; \
        gload16(eB + aOffG0 + kby, aD + ldsRow0); \
        gload16(eB + aOffG1 + kby, aD + ldsRow1); \
        gload16(iB + bOffG0 + kby, bD + ldsRow0); \
        gload16(iB + bOffG1 + kby, bD + ldsRow1); \
    } while (0)

    STAGE(0, 0);
    #pragma unroll
    for (int kb = 0; kb < 8; ++kb) {
        int cur = kb & 1;
        __syncthreads();
        if (kb < 7) STAGE(kb + 1, cur ^ 1);
        const char* aS = smem + cur * 16384;
        const char* bS = smem + 32768 + cur * 16384;
        #pragma unroll
        for (int kk = 0; kk < 2; ++kk) {
            int co = ((kk * 4 + g4) ^ swb) * 16;
            half8 bF[2];
            #pragma unroll
            for (int fn = 0; fn < 2; ++fn)
                bF[fn] = *(const half8*)(const void*)(bS + bRow[fn] + co);
            #pragma unroll
            for (int fm = 0; fm < 4; ++fm) {
                half8 aF = *(const half8*)(const void*)(aS + aRow[fm] + co);
                #pragma unroll
                for (int fn = 0; fn < 2; ++fn)
                    acc[fm][fn] = __builtin_amdgcn_mfma_f32_16x16x32_f16(
                        aF, bF[fn], acc[fm][fn], 0, 0, 0);
            }
        }
    }
#undef STAGE

    #pragma unroll
    for (int fn = 0; fn < 2; ++fn) {
        int cp = nh * 32 + fn * 16 + col16;
        int gate = cp >> 5;
        int jh = pc * 32 + (cp & 31);
        int ct = jh >> 4, jl = jh & 15;
        int cidx = gate * 16 + jl;
        float bv = bsum[gate * HID + jh];
        #pragma unroll
        for (int fm = 0; fm < 4; ++fm)
            #pragma unroll
            for (int r = 0; r < 4; ++r) {
                int row = m0 + mh * 64 + fm * 16 + g4 * 4 + r;
                int t = row >> 8, b = row & 255;
                G0n[(((size_t)t * 64 + ct) * 256 + b) * 64 + cidx] =
                    acc[fm][fn][r] + bv;
            }
    }
}

// ---------------- persistent LSTM: B in regs, A in LDS, flag barrier --------
// R14 = R12 with ONE change: barrier arrival = per-block OWNED flag (sc1
// relaxed store of t+1, no RMW/no contention); wave 0 polls all 64 flags in
// PARALLEL (one lane each, one L3 round) + __all ballot. The pre-store
// __syncthreads drains every wave's sc1 h-stores (vmcnt0), so flag>=t+1
// implies that block's h is L3-visible.
__global__ __launch_bounds__(512, 2) void lstm_persist(
    const unsigned short* __restrict__ hh,     // fp16 Whh [4096][1024]
    unsigned short* __restrict__ hBuf,         // 27 slots of NB*HID fp16
    const float* __restrict__ G0n,
    float* __restrict__ out,
    unsigned int* __restrict__ bar)
{
    extern __shared__ char smem[];
    float* gbuf = (float*)(smem + 131072);

    int bx = blockIdx.x;
    int grp = (bx & 7) >> 1;                     // 0..3
    int ct  = ((bx >> 3) & 31) + 32 * (bx & 1);  // 0..63
    int m0  = grp * 64;
    int jh0 = ct * 16;

    int tid = threadIdx.x;
    int w = tid >> 6;
    int gate = w & 3, mh = w >> 2;
    int lane = tid & 63;
    int col16 = lane & 15, g4 = lane >> 4;

    // flags: group grp owns bar[grp*1024 + i*16], i = 0..63 (64B apart)
    unsigned int* flags = bar + grp * 1024;

    // ---- preload B (this wave's 16 Whh gate-rows) into registers ----
    half8 bB[32];
    {
        const char* bRow = (const char*)hh +
            ((size_t)(gate * HID + jh0 + col16) * HID + g4 * 8) * 2;
        #pragma unroll
        for (int kk = 0; kk < 32; ++kk)
            bB[kk] = *(const half8*)(const void*)(bRow + kk * 64);
    }

    int ml = tid >> 3, jl2 = (tid & 7) * 2;
    float cReg[2] = {0.f, 0.f};

    for (int t = 0; t < SEQW; ++t) {
        const unsigned short* hIn = hBuf + (size_t)t * NB * HID;
        unsigned short* hOut = hBuf + (size_t)(t + 1) * NB * HID;

        // G0 prefetch for THIS step (hides under staging + K-loop)
        f32x2 g0v[4];
        {
            const float* pg = G0n +
                (((size_t)t * 64 + ct) * 256 + (m0 + ml)) * 64 + jl2;
            #pragma unroll
            for (int q = 0; q < 4; ++q) g0v[q] = *(const f32x2*)(pg + q * 16);
        }

        f32x4 acc0 = {0.f, 0.f, 0.f, 0.f};
        f32x4 acc1 = {0.f, 0.f, 0.f, 0.f};

        if (t > 0) {
            {
                const char* hRowB = (const char*)hIn +
                    (size_t)(m0 + lane) * (HID * 2) + w * 256;
                #pragma unroll
                for (int j = 0; j < 4; ++j) {
                    int kk = w * 4 + j;
                    short8 v[4];
                    #pragma unroll
                    for (int q = 0; q < 4; ++q)
                        v[q] = *(const short8*)(const void*)(hRowB + j * 64 + q * 16);
                    #pragma unroll
                    for (int q = 0; q < 4; ++q)
                        *(short8*)(smem + ((kk * 4 + q) * 64 + lane) * 16) = v[q];
                }
            }
            __syncthreads();

            #pragma unroll
            for (int kk = 0; kk < 32; ++kk) {
                const char* slab = smem + (kk * 4 + g4) * 1024;
                half8 a0 = *(const half8*)(const void*)(slab + (mh * 32 + col16) * 16);
                half8 a1 = *(const half8*)(const void*)(slab + (mh * 32 + 16 + col16) * 16);
                acc0 = __builtin_amdgcn_mfma_f32_16x16x32_f16(a0, bB[kk], acc0, 0, 0, 0);
                acc1 = __builtin_amdgcn_mfma_f32_16x16x32_f16(a1, bB[kk], acc1, 0, 0, 0);
            }
        }

        #pragma unroll
        for (int r = 0; r < 4; ++r) {
            gbuf[(gate * 64 + mh * 32 + g4 * 4 + r) * 20 + col16] = acc0[r];
            gbuf[(gate * 64 + mh * 32 + 16 + g4 * 4 + r) * 20 + col16] = acc1[r];
        }
        __syncthreads();

        f32x2 gv[4];
        #pragma unroll
        for (int q = 0; q < 4; ++q)
            gv[q] = *(const f32x2*)&gbuf[(q * 64 + ml) * 20 + jl2];

        float hN[2];
        #pragma unroll
        for (int u = 0; u < 2; ++u) {
            float gi  = gv[0][u] + g0v[0][u];
            float gf  = gv[1][u] + g0v[1][u];
            float gg_ = gv[2][u] + g0v[2][u];
            float go  = gv[3][u] + g0v[3][u];
            float si = 1.0f / (1.0f + expf(-gi));
            float sf = 1.0f / (1.0f + expf(-gf));
            float so = 1.0f / (1.0f + expf(-go));
            float tg = tanhf(gg_);
            float cN = sf * cReg[u] + si * tg;
            hN[u] = so * tanhf(cN);
            cReg[u] = cN;
        }
        size_t p = (size_t)(m0 + ml) * HID + jh0 + jl2;
        if (t == SEQW - 1) {
            *(f32x2*)(out + p) = (f32x2){hN[0], hN[1]};
        } else {
            unsigned int hv = (unsigned int)f16bits((_Float16)hN[0]) |
                              ((unsigned int)f16bits((_Float16)hN[1]) << 16);
            __hip_atomic_store((unsigned int*)(hOut + p), hv,
                               __ATOMIC_RELAXED, __HIP_MEMORY_SCOPE_AGENT);

            __syncthreads();   // ALL waves' h sc1-stores drained (L3-visible)
            unsigned int t1 = (unsigned int)(t + 1);
            if (tid == 0)
                __hip_atomic_store(flags + ct * 16, t1,
                                   __ATOMIC_RELAXED, __HIP_MEMORY_SCOPE_AGENT);
            if (w == 0) {
                for (;;) {
                    unsigned int v = __hip_atomic_load(
                        flags + lane * 16, __ATOMIC_RELAXED,
                        __HIP_MEMORY_SCOPE_AGENT);
                    if (__all(v >= t1)) break;
                    __builtin_amdgcn_s_sleep(1);
                }
            }
            __syncthreads();
        }
    }
}

extern "C" void kernel_launch(void* const* d_in, const int* in_sizes, int n_in,
                              void* d_out, int out_size, void* d_ws, size_t ws_size,
                              hipStream_t stream) {
    const int*   qv   = (const int*)d_in[0];
    const float* Wemb = (const float*)d_in[2];
    const float* Wih  = (const float*)d_in[3];
    const float* Whh  = (const float*)d_in[4];
    const float* b_ih = (const float*)d_in[5];
    const float* b_hh = (const float*)d_in[6];
    float* out = (float*)d_out;

    char* ws = (char*)d_ws;
    size_t off = 0;
    unsigned short* eHi  = (unsigned short*)(ws + off); off += (size_t)MTOT * EMBD * 2;
    unsigned short* ih   = (unsigned short*)(ws + off); off += (size_t)NGATE * EMBD * 2;
    unsigned short* hh   = (unsigned short*)(ws + off); off += (size_t)NGATE * HID * 2;
    unsigned short* hBuf = (unsigned short*)(ws + off); off += (size_t)(SEQW + 1) * NB * HID * 2;
    float* bsum          = (float*)(ws + off);          off += (size_t)NGATE * 4;
    unsigned int* bar    = (unsigned int*)(ws + off);   off += 16384;
    off = (off + 255) & ~(size_t)255;
    float* G0n           = (float*)(ws + off);          off += (size_t)MTOT * NGATE * 4; // 109 MB
    unsigned short* WembT = (unsigned short*)G0n;       // aliases G0n (dead before pregemm)

    init_kernel<<<NB * HID / 256, 256, 0, stream>>>(hBuf, bar);
    transp_kernel<<<dim3(782, 8), 256, 0, stream>>>(Wemb, WembT);
    embed_kernel<<<MTOT / 4, 256, 0, stream>>>(qv, WembT, eHi);
    convw_kernel<<<NGATE, 256, 0, stream>>>(Wih, Whh, b_ih, b_hh, ih, hh, bsum);
    pregemm_kernel<<<1664, 512, 0, stream>>>(eHi, ih, bsum, G0n);

    lstm_persist<<<256, 512, 151552, stream>>>(hh, hBuf, G0n, out, bar);
}

// Round 15
// 209.191 us; speedup vs baseline: 1.7032x; 1.3413x over previous
//
#include <hip/hip_runtime.h>
#include <hip/hip_bf16.h>

#define VOCAB 50000
#define EMBD  512
#define HID   1024
#define NB    256
#define SEQW  26
#define MTOT  (SEQW * NB)   /* 6656 */
#define NGATE (4 * HID)     /* 4096 */

typedef short short8 __attribute__((ext_vector_type(8)));
typedef _Float16 half8 __attribute__((ext_vector_type(8)));
typedef float f32x4  __attribute__((ext_vector_type(4)));
typedef float f32x2  __attribute__((ext_vector_type(2)));

__device__ __forceinline__ unsigned short f16bits(_Float16 h) {
    union { _Float16 h; unsigned short u; } cv; cv.h = h; return cv.u;
}

__device__ __forceinline__ void gload16(const void* g, void* l) {
    __builtin_amdgcn_global_load_lds(
        (const __attribute__((address_space(1))) void*)g,
        (__attribute__((address_space(3))) void*)l, 16, 0, 0);
}

// ---------------- init: zero h slot0 + barrier flags ----------------
__global__ void init_kernel(unsigned short* __restrict__ hBuf,
                            unsigned int* __restrict__ bar) {
    int idx = blockIdx.x * blockDim.x + threadIdx.x;  // 1024 x 256
    hBuf[idx] = 0;                                     // slot 0 = h_0 = 0
    if (idx < 4096) bar[idx] = 0;
}

// ---------------- Wemb transpose: [512][50000] f32 -> WembT [50000][512] f16
__global__ void transp_kernel(const float* __restrict__ W,
                              unsigned short* __restrict__ WT) {
    __shared__ _Float16 tile[64][72];
    int v0 = blockIdx.x * 64;
    int e0 = blockIdx.y * 64;
    int tid = threadIdx.x;

    int e_loc = tid >> 2, q = tid & 3;
    int vq = q * 16;
    if (v0 + vq < VOCAB) {
        const float* src = W + (size_t)(e0 + e_loc) * VOCAB + v0 + vq;
        #pragma unroll
        for (int j = 0; j < 4; ++j) {
            f32x4 x = *(const f32x4*)(src + 4 * j);
            #pragma unroll
            for (int i = 0; i < 4; ++i)
                tile[vq + 4 * j + i][e_loc] = (_Float16)x[i];
        }
    }
    __syncthreads();

    int v_loc = tid >> 2;
    int ec = q * 16;
    int v = v0 + v_loc;
    if (v < VOCAB) {
        short8* dst = (short8*)(WT + (size_t)v * EMBD + e0 + ec);
        dst[0] = *(const short8*)&tile[v_loc][ec];
        dst[1] = *(const short8*)&tile[v_loc][ec + 8];
    }
}

// ---------------- embedding: row-gather from WembT + tanh -> fp16 -----------
__global__ void embed_kernel(const int* __restrict__ qv,
                             const unsigned short* __restrict__ WT,
                             unsigned short* __restrict__ eHi) {
    int pair = blockIdx.x * 4 + (threadIdx.x >> 6);
    int t = pair >> 8, b = pair & 255;
    int lane = threadIdx.x & 63;
    int tok = qv[b * SEQW + t];
    short8 out = {};
    if (tok > 0) {
        short8 v = *(const short8*)(WT + (size_t)(tok - 1) * EMBD + lane * 8);
        #pragma unroll
        for (int i = 0; i < 8; ++i) {
            union { short s; _Float16 h; } cv; cv.s = v[i];
            out[i] = (short)f16bits((_Float16)tanhf((float)cv.h));
        }
    }
    *(short8*)(eHi + (size_t)pair * EMBD + lane * 8) = out;
}

// ---------------- weight conversion: ih fp16, hh fp16, bsum -----------------
__global__ void convw_kernel(const float* __restrict__ Wih,
                             const float* __restrict__ Whh,
                             const float* __restrict__ b_ih,
                             const float* __restrict__ b_hh,
                             unsigned short* __restrict__ ih,
                             unsigned short* __restrict__ hh,
                             float* __restrict__ bsum) {
    int j = blockIdx.x; // 0..4095
    if (threadIdx.x == 0) bsum[j] = b_ih[j] + b_hh[j];
    for (int col = threadIdx.x; col < EMBD; col += blockDim.x)
        ih[(size_t)j * EMBD + col] = f16bits((_Float16)Wih[(size_t)j * EMBD + col]);
    for (int col = threadIdx.x; col < HID; col += blockDim.x)
        hh[(size_t)j * HID + col] = f16bits((_Float16)Whh[(size_t)j * HID + col]);
}

// ---------------- pre-GEMM v2: LDS-staged (m97-style), fp16 1-term ----------
__global__ __launch_bounds__(512, 2) void pregemm_kernel(
    const unsigned short* __restrict__ eHi,
    const unsigned short* __restrict__ ih,
    const float* __restrict__ bsum,
    float* __restrict__ G0n)
{
    __shared__ char smem[65536];   // A dbuf [2][16KB] @0, B dbuf [2][16KB] @32768

    int id = blockIdx.x;
    int xcd = id & 7, lid = id >> 3;
    int pc = xcd * 4 + (lid & 3);   // 0..31
    int pm = lid >> 2;              // 0..51
    int m0 = pm * 128;

    int tid = threadIdx.x;
    int w = tid >> 6;               // 0..7
    int mh = w >> 2, nh = w & 3;
    int lane = tid & 63;
    int col16 = lane & 15, g4 = lane >> 4;

    int sr = lane >> 3, sc = lane & 7;
    int ra0 = w * 16 + sr, ra1 = ra0 + 8;
    const char* eB = (const char*)eHi;
    const char* iB = (const char*)ih;
    size_t aOffG0 = (size_t)(m0 + ra0) * 1024 + (size_t)(((sc ^ (ra0 & 7))) * 16);
    size_t aOffG1 = (size_t)(m0 + ra1) * 1024 + (size_t)(((sc ^ (ra1 & 7))) * 16);
    int gb0 = (ra0 >> 5) * 1024 + pc * 32 + (ra0 & 31);
    int gb1 = (ra1 >> 5) * 1024 + pc * 32 + (ra1 & 31);
    size_t bOffG0 = (size_t)gb0 * 1024 + (size_t)(((sc ^ (ra0 & 7))) * 16);
    size_t bOffG1 = (size_t)gb1 * 1024 + (size_t)(((sc ^ (ra1 & 7))) * 16);
    int ldsRow0 = (w * 16) * 128;
    int ldsRow1 = (w * 16 + 8) * 128;

    f32x4 acc[4][2];
    #pragma unroll
    for (int fm = 0; fm < 4; ++fm)
        #pragma unroll
        for (int fn = 0; fn < 2; ++fn)
            acc[fm][fn] = (f32x4){0.f, 0.f, 0.f, 0.f};

    int swb = col16 & 7;
    int aRow[4], bRow[2];
    #pragma unroll
    for (int fm = 0; fm < 4; ++fm) aRow[fm] = (mh * 64 + fm * 16 + col16) * 128;
    #pragma unroll
    for (int fn = 0; fn < 2; ++fn) bRow[fn] = (nh * 32 + fn * 16 + col16) * 128;

#define STAGE(kb, buf) do { \
        int kby = (kb) * 128; \
        char* aD = smem + (buf) * 16384; \
        char* bD = smem + 32768 + (buf) * 16384; \
        gload16(eB + aOffG0 + kby, aD + ldsRow0); \
        gload16(eB + aOffG1 + kby, aD + ldsRow1); \
        gload16(iB + bOffG0 + kby, bD + ldsRow0); \
        gload16(iB + bOffG1 + kby, bD + ldsRow1); \
    } while (0)

    STAGE(0, 0);
    #pragma unroll
    for (int kb = 0; kb < 8; ++kb) {
        int cur = kb & 1;
        __syncthreads();
        if (kb < 7) STAGE(kb + 1, cur ^ 1);
        const char* aS = smem + cur * 16384;
        const char* bS = smem + 32768 + cur * 16384;
        #pragma unroll
        for (int kk = 0; kk < 2; ++kk) {
            int co = ((kk * 4 + g4) ^ swb) * 16;
            half8 bF[2];
            #pragma unroll
            for (int fn = 0; fn < 2; ++fn)
                bF[fn] = *(const half8*)(const void*)(bS + bRow[fn] + co);
            #pragma unroll
            for (int fm = 0; fm < 4; ++fm) {
                half8 aF = *(const half8*)(const void*)(aS + aRow[fm] + co);
                #pragma unroll
                for (int fn = 0; fn < 2; ++fn)
                    acc[fm][fn] = __builtin_amdgcn_mfma_f32_16x16x32_f16(
                        aF, bF[fn], acc[fm][fn], 0, 0, 0);
            }
        }
    }
#undef STAGE

    #pragma unroll
    for (int fn = 0; fn < 2; ++fn) {
        int cp = nh * 32 + fn * 16 + col16;
        int gate = cp >> 5;
        int jh = pc * 32 + (cp & 31);
        int ct = jh >> 4, jl = jh & 15;
        int cidx = gate * 16 + jl;
        float bv = bsum[gate * HID + jh];
        #pragma unroll
        for (int fm = 0; fm < 4; ++fm)
            #pragma unroll
            for (int r = 0; r < 4; ++r) {
                int row = m0 + mh * 64 + fm * 16 + g4 * 4 + r;
                int t = row >> 8, b = row & 255;
                G0n[(((size_t)t * 64 + ct) * 256 + b) * 64 + cidx] =
                    acc[fm][fn][r] + bv;
            }
    }
}

// ---------------- persistent LSTM: XCD-local groups, K-split waves ----------
// 256 blocks x 512 threads, 1 block/CU. Group = bx&7 (32 blocks, same XCD
// under round-robin dispatch — perf heuristic only, correctness via sc1/L3).
// Group owns batch rows [grp*32,+32) x all 4096 gate-cols; block lid=bx>>3
// owns jh [lid*32,+32) x 4 gates. 8 waves = kq(2, K=512 each) x gate(4);
// wave N=32 (2 Nfrags), M=32 (2 Mfrags); B = 128 VGPR/lane, loaded once.
// A (32x1024 fp16 = 64KB) in LDS row-major + XOR((row&7)<<4) swizzle.
// K-partials: dual gbuf, summed in epilogue. Barrier: per-block flag +
// wave-parallel poll (32 flags).
__global__ __launch_bounds__(512, 2) void lstm_persist(
    const unsigned short* __restrict__ hh,     // fp16 Whh [4096][1024]
    unsigned short* __restrict__ hBuf,         // 27 slots of NB*HID fp16
    const float* __restrict__ G0n,
    float* __restrict__ out,
    unsigned int* __restrict__ bar)
{
    extern __shared__ char smem[];
    // [0,65536): A [32][2048B] XOR-swizzled; [65536,102400): gbuf[2][4][32][36]
    float* gbuf = (float*)(smem + 65536);

    int bx = blockIdx.x;
    int grp = bx & 7;                 // XCD-local group
    int lid = bx >> 3;                // 0..31
    int m0  = grp * 32;
    int jh0 = lid * 32;

    int tid = threadIdx.x;
    int w = tid >> 6;
    int kq = w >> 2, gate = w & 3;
    int lane = tid & 63;
    int col16 = lane & 15, g4 = lane >> 4;

    unsigned int* flags = bar + grp * 512;   // 32 flags, 64B apart

    // ---- preload B: wave's 32 Whh gate-cols x K-half into registers ----
    half8 bB[2][16];
    #pragma unroll
    for (int nf = 0; nf < 2; ++nf) {
        const char* bRow = (const char*)hh +
            (((size_t)(gate * HID + jh0 + nf * 16 + col16)) * HID + kq * 512 + g4 * 8) * 2;
        #pragma unroll
        for (int kk = 0; kk < 16; ++kk)
            bB[nf][kk] = *(const half8*)(const void*)(bRow + kk * 64);
    }

    // stage mapping: srow = tid>>4 (0..31), sc = tid&15
    int srow = tid >> 4, sc = tid & 15;
    int swz = (srow & 7) << 4;
    // frag-read swizzle
    int swr = (col16 & 7) << 4;
    // epilogue mapping: ml = tid>>4 (0..31), jl2 = (tid&15)*2
    int ml = srow, jl2 = sc * 2;
    int jh = jh0 + jl2;
    int ctE = jh >> 4, jlE = jh & 15;

    float cReg[2] = {0.f, 0.f};

    for (int t = 0; t < SEQW; ++t) {
        const unsigned short* hIn = hBuf + (size_t)t * NB * HID;
        unsigned short* hOut = hBuf + (size_t)(t + 1) * NB * HID;

        // G0 prefetch for THIS step (drains under staging + K-loop)
        f32x2 g0v[4];
        {
            const float* pg = G0n +
                (((size_t)t * 64 + ctE) * 256 + (m0 + ml)) * 64 + jlE;
            #pragma unroll
            for (int q = 0; q < 4; ++q) g0v[q] = *(const f32x2*)(pg + q * 16);
        }

        f32x4 acc[2][2];
        #pragma unroll
        for (int mf = 0; mf < 2; ++mf)
            #pragma unroll
            for (int nf = 0; nf < 2; ++nf)
                acc[mf][nf] = (f32x4){0.f, 0.f, 0.f, 0.f};

        if (t > 0) {
            // ---- cooperative A stage: 64KB, row-major + XOR swizzle ----
            {
                const char* hRowB = (const char*)hIn + (size_t)(m0 + srow) * (HID * 2);
                short8 v[8];
                #pragma unroll
                for (int j = 0; j < 8; ++j)
                    v[j] = *(const short8*)(const void*)(hRowB + j * 256 + sc * 16);
                #pragma unroll
                for (int j = 0; j < 8; ++j)
                    *(short8*)(smem + srow * 2048 + ((j * 256 + sc * 16) ^ swz)) = v[j];
            }
            __syncthreads();

            // ---- K loop: A from LDS, B from registers ----
            #pragma unroll
            for (int kk = 0; kk < 16; ++kk) {
                int kb = kq * 1024 + kk * 64 + g4 * 16;
                half8 a0 = *(const half8*)(const void*)(smem + col16 * 2048 + (kb ^ swr));
                half8 a1 = *(const half8*)(const void*)(smem + (col16 + 16) * 2048 + (kb ^ swr));
                acc[0][0] = __builtin_amdgcn_mfma_f32_16x16x32_f16(a0, bB[0][kk], acc[0][0], 0, 0, 0);
                acc[0][1] = __builtin_amdgcn_mfma_f32_16x16x32_f16(a0, bB[1][kk], acc[0][1], 0, 0, 0);
                acc[1][0] = __builtin_amdgcn_mfma_f32_16x16x32_f16(a1, bB[0][kk], acc[1][0], 0, 0, 0);
                acc[1][1] = __builtin_amdgcn_mfma_f32_16x16x32_f16(a1, bB[1][kk], acc[1][1], 0, 0, 0);
            }
        }

        // scatter K-partials: gbuf[kq][gate][row][col], row stride 36
        #pragma unroll
        for (int mf = 0; mf < 2; ++mf)
            #pragma unroll
            for (int nf = 0; nf < 2; ++nf)
                #pragma unroll
                for (int r = 0; r < 4; ++r)
                    gbuf[(((kq * 4 + gate) * 32) + mf * 16 + g4 * 4 + r) * 36
                         + nf * 16 + col16] = acc[mf][nf][r];
        __syncthreads();

        // ---- epilogue: sum 2 K-partials, fused gates, 2 adjacent cells ----
        f32x2 gv[4];
        #pragma unroll
        for (int q = 0; q < 4; ++q) {
            f32x2 p0 = *(const f32x2*)&gbuf[((q) * 32 + ml) * 36 + jl2];
            f32x2 p1 = *(const f32x2*)&gbuf[((4 + q) * 32 + ml) * 36 + jl2];
            gv[q] = p0 + p1;
        }

        float hN[2];
        #pragma unroll
        for (int u = 0; u < 2; ++u) {
            float gi  = gv[0][u] + g0v[0][u];
            float gf  = gv[1][u] + g0v[1][u];
            float gg_ = gv[2][u] + g0v[2][u];
            float go  = gv[3][u] + g0v[3][u];
            float si = 1.0f / (1.0f + expf(-gi));
            float sf = 1.0f / (1.0f + expf(-gf));
            float so = 1.0f / (1.0f + expf(-go));
            float tg = tanhf(gg_);
            float cN = sf * cReg[u] + si * tg;
            hN[u] = so * tanhf(cN);
            cReg[u] = cN;
        }
        size_t p = (size_t)(m0 + ml) * HID + jh;
        if (t == SEQW - 1) {
            *(f32x2*)(out + p) = (f32x2){hN[0], hN[1]};
        } else {
            unsigned int hv = (unsigned int)f16bits((_Float16)hN[0]) |
                              ((unsigned int)f16bits((_Float16)hN[1]) << 16);
            __hip_atomic_store((unsigned int*)(hOut + p), hv,
                               __ATOMIC_RELAXED, __HIP_MEMORY_SCOPE_AGENT);

            __syncthreads();   // ALL waves' h sc1-stores drained (L3-visible)
            unsigned int t1 = (unsigned int)(t + 1);
            if (tid == 0)
                __hip_atomic_store(flags + lid * 16, t1,
                                   __ATOMIC_RELAXED, __HIP_MEMORY_SCOPE_AGENT);
            if (w == 0) {
                for (;;) {
                    unsigned int v = __hip_atomic_load(
                        flags + (lane & 31) * 16, __ATOMIC_RELAXED,
                        __HIP_MEMORY_SCOPE_AGENT);
                    if (__all(v >= t1)) break;
                    __builtin_amdgcn_s_sleep(1);
                }
            }
            __syncthreads();
        }
    }
}

extern "C" void kernel_launch(void* const* d_in, const int* in_sizes, int n_in,
                              void* d_out, int out_size, void* d_ws, size_t ws_size,
                              hipStream_t stream) {
    const int*   qv   = (const int*)d_in[0];
    const float* Wemb = (const float*)d_in[2];
    const float* Wih  = (const float*)d_in[3];
    const float* Whh  = (const float*)d_in[4];
    const float* b_ih = (const float*)d_in[5];
    const float* b_hh = (const float*)d_in[6];
    float* out = (float*)d_out;

    char* ws = (char*)d_ws;
    size_t off = 0;
    unsigned short* eHi  = (unsigned short*)(ws + off); off += (size_t)MTOT * EMBD * 2;
    unsigned short* ih   = (unsigned short*)(ws + off); off += (size_t)NGATE * EMBD * 2;
    unsigned short* hh   = (unsigned short*)(ws + off); off += (size_t)NGATE * HID * 2;
    unsigned short* hBuf = (unsigned short*)(ws + off); off += (size_t)(SEQW + 1) * NB * HID * 2;
    float* bsum          = (float*)(ws + off);          off += (size_t)NGATE * 4;
    unsigned int* bar    = (unsigned int*)(ws + off);   off += 16384;
    off = (off + 255) & ~(size_t)255;
    float* G0n           = (float*)(ws + off);          off += (size_t)MTOT * NGATE * 4; // 109 MB
    unsigned short* WembT = (unsigned short*)G0n;       // aliases G0n (dead before pregemm)

    init_kernel<<<NB * HID / 256, 256, 0, stream>>>(hBuf, bar);
    transp_kernel<<<dim3(782, 8), 256, 0, stream>>>(Wemb, WembT);
    embed_kernel<<<MTOT / 4, 256, 0, stream>>>(qv, WembT, eHi);
    convw_kernel<<<NGATE, 256, 0, stream>>>(Wih, Whh, b_ih, b_hh, ih, hh, bsum);
    pregemm_kernel<<<1664, 512, 0, stream>>>(eHi, ih, bsum, G0n);

    lstm_persist<<<256, 512, 102400, stream>>>(hh, hBuf, G0n, out, bar);
}

// Round 16
// 206.688 us; speedup vs baseline: 1.7239x; 1.0121x over previous
//
#include <hip/hip_runtime.h>
#include <hip/hip_bf16.h>

#define VOCAB 50000
#define EMBD  512
#define HID   1024
#define NB    256
#define SEQW  26
#define MTOT  (SEQW * NB)   /* 6656 */
#define NGATE (4 * HID)     /* 4096 */

typedef short short8 __attribute__((ext_vector_type(8)));
typedef _Float16 half8 __attribute__((ext_vector_type(8)));
typedef _Float16 half2v __attribute__((ext_vector_type(2)));
typedef float f32x4  __attribute__((ext_vector_type(4)));
typedef float f32x2  __attribute__((ext_vector_type(2)));

__device__ __forceinline__ unsigned short f16bits(_Float16 h) {
    union { _Float16 h; unsigned short u; } cv; cv.h = h; return cv.u;
}

__device__ __forceinline__ void gload16(const void* g, void* l) {
    __builtin_amdgcn_global_load_lds(
        (const __attribute__((address_space(1))) void*)g,
        (__attribute__((address_space(3))) void*)l, 16, 0, 0);
}

// ---------------- init: zero h slot0 + barrier flags ----------------
__global__ void init_kernel(unsigned short* __restrict__ hBuf,
                            unsigned int* __restrict__ bar) {
    int idx = blockIdx.x * blockDim.x + threadIdx.x;  // 1024 x 256
    hBuf[idx] = 0;                                     // slot 0 = h_0 = 0
    if (idx < 4096) bar[idx] = 0;
}

// ---------------- Wemb transpose: [512][50000] f32 -> WembT [50000][512] f16
__global__ void transp_kernel(const float* __restrict__ W,
                              unsigned short* __restrict__ WT) {
    __shared__ _Float16 tile[64][72];
    int v0 = blockIdx.x * 64;
    int e0 = blockIdx.y * 64;
    int tid = threadIdx.x;

    int e_loc = tid >> 2, q = tid & 3;
    int vq = q * 16;
    if (v0 + vq < VOCAB) {
        const float* src = W + (size_t)(e0 + e_loc) * VOCAB + v0 + vq;
        #pragma unroll
        for (int j = 0; j < 4; ++j) {
            f32x4 x = *(const f32x4*)(src + 4 * j);
            #pragma unroll
            for (int i = 0; i < 4; ++i)
                tile[vq + 4 * j + i][e_loc] = (_Float16)x[i];
        }
    }
    __syncthreads();

    int v_loc = tid >> 2;
    int ec = q * 16;
    int v = v0 + v_loc;
    if (v < VOCAB) {
        short8* dst = (short8*)(WT + (size_t)v * EMBD + e0 + ec);
        dst[0] = *(const short8*)&tile[v_loc][ec];
        dst[1] = *(const short8*)&tile[v_loc][ec + 8];
    }
}

// ---------------- embedding: row-gather from WembT + tanh -> fp16 -----------
__global__ void embed_kernel(const int* __restrict__ qv,
                             const unsigned short* __restrict__ WT,
                             unsigned short* __restrict__ eHi) {
    int pair = blockIdx.x * 4 + (threadIdx.x >> 6);
    int t = pair >> 8, b = pair & 255;
    int lane = threadIdx.x & 63;
    int tok = qv[b * SEQW + t];
    short8 out = {};
    if (tok > 0) {
        short8 v = *(const short8*)(WT + (size_t)(tok - 1) * EMBD + lane * 8);
        #pragma unroll
        for (int i = 0; i < 8; ++i) {
            union { short s; _Float16 h; } cv; cv.s = v[i];
            out[i] = (short)f16bits((_Float16)tanhf((float)cv.h));
        }
    }
    *(short8*)(eHi + (size_t)pair * EMBD + lane * 8) = out;
}

// ---------------- weight conversion: ih fp16, hh fp16, bsum -----------------
__global__ void convw_kernel(const float* __restrict__ Wih,
                             const float* __restrict__ Whh,
                             const float* __restrict__ b_ih,
                             const float* __restrict__ b_hh,
                             unsigned short* __restrict__ ih,
                             unsigned short* __restrict__ hh,
                             float* __restrict__ bsum) {
    int j = blockIdx.x; // 0..4095
    if (threadIdx.x == 0) bsum[j] = b_ih[j] + b_hh[j];
    for (int col = threadIdx.x; col < EMBD; col += blockDim.x)
        ih[(size_t)j * EMBD + col] = f16bits((_Float16)Wih[(size_t)j * EMBD + col]);
    for (int col = threadIdx.x; col < HID; col += blockDim.x)
        hh[(size_t)j * HID + col] = f16bits((_Float16)Whh[(size_t)j * HID + col]);
}

// ---------------- pre-GEMM: LDS-staged, fp16 1-term, G0 stored FP16 ---------
__global__ __launch_bounds__(512, 2) void pregemm_kernel(
    const unsigned short* __restrict__ eHi,
    const unsigned short* __restrict__ ih,
    const float* __restrict__ bsum,
    unsigned short* __restrict__ G0h)
{
    __shared__ char smem[65536];   // A dbuf [2][16KB] @0, B dbuf [2][16KB] @32768

    int id = blockIdx.x;
    int xcd = id & 7, lid = id >> 3;
    int pc = xcd * 4 + (lid & 3);   // 0..31
    int pm = lid >> 2;              // 0..51
    int m0 = pm * 128;

    int tid = threadIdx.x;
    int w = tid >> 6;               // 0..7
    int mh = w >> 2, nh = w & 3;
    int lane = tid & 63;
    int col16 = lane & 15, g4 = lane >> 4;

    int sr = lane >> 3, sc = lane & 7;
    int ra0 = w * 16 + sr, ra1 = ra0 + 8;
    const char* eB = (const char*)eHi;
    const char* iB = (const char*)ih;
    size_t aOffG0 = (size_t)(m0 + ra0) * 1024 + (size_t)(((sc ^ (ra0 & 7))) * 16);
    size_t aOffG1 = (size_t)(m0 + ra1) * 1024 + (size_t)(((sc ^ (ra1 & 7))) * 16);
    int gb0 = (ra0 >> 5) * 1024 + pc * 32 + (ra0 & 31);
    int gb1 = (ra1 >> 5) * 1024 + pc * 32 + (ra1 & 31);
    size_t bOffG0 = (size_t)gb0 * 1024 + (size_t)(((sc ^ (ra0 & 7))) * 16);
    size_t bOffG1 = (size_t)gb1 * 1024 + (size_t)(((sc ^ (ra1 & 7))) * 16);
    int ldsRow0 = (w * 16) * 128;
    int ldsRow1 = (w * 16 + 8) * 128;

    f32x4 acc[4][2];
    #pragma unroll
    for (int fm = 0; fm < 4; ++fm)
        #pragma unroll
        for (int fn = 0; fn < 2; ++fn)
            acc[fm][fn] = (f32x4){0.f, 0.f, 0.f, 0.f};

    int swb = col16 & 7;
    int aRow[4], bRow[2];
    #pragma unroll
    for (int fm = 0; fm < 4; ++fm) aRow[fm] = (mh * 64 + fm * 16 + col16) * 128;
    #pragma unroll
    for (int fn = 0; fn < 2; ++fn) bRow[fn] = (nh * 32 + fn * 16 + col16) * 128;

#define STAGE(kb, buf) do { \
        int kby = (kb) * 128; \
        char* aD = smem + (buf) * 16384; \
        char* bD = smem + 32768 + (buf) * 16384; \
        gload16(eB + aOffG0 + kby, aD + ldsRow0); \
        gload16(eB + aOffG1 + kby, aD + ldsRow1); \
        gload16(iB + bOffG0 + kby, bD + ldsRow0); \
        gload16(iB + bOffG1 + kby, bD + ldsRow1); \
    } while (0)

    STAGE(0, 0);
    #pragma unroll
    for (int kb = 0; kb < 8; ++kb) {
        int cur = kb & 1;
        __syncthreads();
        if (kb < 7) STAGE(kb + 1, cur ^ 1);
        const char* aS = smem + cur * 16384;
        const char* bS = smem + 32768 + cur * 16384;
        #pragma unroll
        for (int kk = 0; kk < 2; ++kk) {
            int co = ((kk * 4 + g4) ^ swb) * 16;
            half8 bF[2];
            #pragma unroll
            for (int fn = 0; fn < 2; ++fn)
                bF[fn] = *(const half8*)(const void*)(bS + bRow[fn] + co);
            #pragma unroll
            for (int fm = 0; fm < 4; ++fm) {
                half8 aF = *(const half8*)(const void*)(aS + aRow[fm] + co);
                #pragma unroll
                for (int fn = 0; fn < 2; ++fn)
                    acc[fm][fn] = __builtin_amdgcn_mfma_f32_16x16x32_f16(
                        aF, bF[fn], acc[fm][fn], 0, 0, 0);
            }
        }
    }
#undef STAGE

    #pragma unroll
    for (int fn = 0; fn < 2; ++fn) {
        int cp = nh * 32 + fn * 16 + col16;
        int gate = cp >> 5;
        int jh = pc * 32 + (cp & 31);
        int ct = jh >> 4, jl = jh & 15;
        int cidx = gate * 16 + jl;
        float bv = bsum[gate * HID + jh];
        #pragma unroll
        for (int fm = 0; fm < 4; ++fm)
            #pragma unroll
            for (int r = 0; r < 4; ++r) {
                int row = m0 + mh * 64 + fm * 16 + g4 * 4 + r;
                int t = row >> 8, b = row & 255;
                G0h[(((size_t)t * 64 + ct) * 256 + b) * 64 + cidx] =
                    f16bits((_Float16)(acc[fm][fn][r] + bv));
            }
    }
}

// ---------------- persistent LSTM: XCD-local groups, K-split, fp16 G0 -------
// R16 = R15 with ONE change: G0 stream is fp16 (half HBM traffic).
__global__ __launch_bounds__(512, 2) void lstm_persist(
    const unsigned short* __restrict__ hh,     // fp16 Whh [4096][1024]
    unsigned short* __restrict__ hBuf,         // 27 slots of NB*HID fp16
    const unsigned short* __restrict__ G0h,    // fp16 G0 [t][ct][b][64]
    float* __restrict__ out,
    unsigned int* __restrict__ bar)
{
    extern __shared__ char smem[];
    // [0,65536): A [32][2048B] XOR-swizzled; [65536,102400): gbuf[2][4][32][36]
    float* gbuf = (float*)(smem + 65536);

    int bx = blockIdx.x;
    int grp = bx & 7;                 // XCD-local group
    int lid = bx >> 3;                // 0..31
    int m0  = grp * 32;
    int jh0 = lid * 32;

    int tid = threadIdx.x;
    int w = tid >> 6;
    int kq = w >> 2, gate = w & 3;
    int lane = tid & 63;
    int col16 = lane & 15, g4 = lane >> 4;

    unsigned int* flags = bar + grp * 512;   // 32 flags, 64B apart

    // ---- preload B: wave's 32 Whh gate-cols x K-half into registers ----
    half8 bB[2][16];
    #pragma unroll
    for (int nf = 0; nf < 2; ++nf) {
        const char* bRow = (const char*)hh +
            (((size_t)(gate * HID + jh0 + nf * 16 + col16)) * HID + kq * 512 + g4 * 8) * 2;
        #pragma unroll
        for (int kk = 0; kk < 16; ++kk)
            bB[nf][kk] = *(const half8*)(const void*)(bRow + kk * 64);
    }

    int srow = tid >> 4, sc = tid & 15;
    int swz = (srow & 7) << 4;
    int swr = (col16 & 7) << 4;
    int ml = srow, jl2 = sc * 2;
    int jh = jh0 + jl2;
    int ctE = jh >> 4, jlE = jh & 15;

    float cReg[2] = {0.f, 0.f};

    for (int t = 0; t < SEQW; ++t) {
        const unsigned short* hIn = hBuf + (size_t)t * NB * HID;
        unsigned short* hOut = hBuf + (size_t)(t + 1) * NB * HID;

        // G0 prefetch for THIS step (fp16, drains under staging + K-loop)
        f32x2 g0v[4];
        {
            const unsigned short* pg = G0h +
                (((size_t)t * 64 + ctE) * 256 + (m0 + ml)) * 64 + jlE;
            #pragma unroll
            for (int q = 0; q < 4; ++q) {
                half2v hv = *(const half2v*)(const void*)(pg + q * 16);
                g0v[q] = (f32x2){(float)hv[0], (float)hv[1]};
            }
        }

        f32x4 acc[2][2];
        #pragma unroll
        for (int mf = 0; mf < 2; ++mf)
            #pragma unroll
            for (int nf = 0; nf < 2; ++nf)
                acc[mf][nf] = (f32x4){0.f, 0.f, 0.f, 0.f};

        if (t > 0) {
            // ---- cooperative A stage: 64KB, row-major + XOR swizzle ----
            {
                const char* hRowB = (const char*)hIn + (size_t)(m0 + srow) * (HID * 2);
                short8 v[8];
                #pragma unroll
                for (int j = 0; j < 8; ++j)
                    v[j] = *(const short8*)(const void*)(hRowB + j * 256 + sc * 16);
                #pragma unroll
                for (int j = 0; j < 8; ++j)
                    *(short8*)(smem + srow * 2048 + ((j * 256 + sc * 16) ^ swz)) = v[j];
            }
            __syncthreads();

            // ---- K loop: A from LDS, B from registers ----
            #pragma unroll
            for (int kk = 0; kk < 16; ++kk) {
                int kb = kq * 1024 + kk * 64 + g4 * 16;
                half8 a0 = *(const half8*)(const void*)(smem + col16 * 2048 + (kb ^ swr));
                half8 a1 = *(const half8*)(const void*)(smem + (col16 + 16) * 2048 + (kb ^ swr));
                acc[0][0] = __builtin_amdgcn_mfma_f32_16x16x32_f16(a0, bB[0][kk], acc[0][0], 0, 0, 0);
                acc[0][1] = __builtin_amdgcn_mfma_f32_16x16x32_f16(a0, bB[1][kk], acc[0][1], 0, 0, 0);
                acc[1][0] = __builtin_amdgcn_mfma_f32_16x16x32_f16(a1, bB[0][kk], acc[1][0], 0, 0, 0);
                acc[1][1] = __builtin_amdgcn_mfma_f32_16x16x32_f16(a1, bB[1][kk], acc[1][1], 0, 0, 0);
            }
        }

        // scatter K-partials: gbuf[kq][gate][row][col], row stride 36
        #pragma unroll
        for (int mf = 0; mf < 2; ++mf)
            #pragma unroll
            for (int nf = 0; nf < 2; ++nf)
                #pragma unroll
                for (int r = 0; r < 4; ++r)
                    gbuf[(((kq * 4 + gate) * 32) + mf * 16 + g4 * 4 + r) * 36
                         + nf * 16 + col16] = acc[mf][nf][r];
        __syncthreads();

        // ---- epilogue: sum 2 K-partials, fused gates, 2 adjacent cells ----
        f32x2 gv[4];
        #pragma unroll
        for (int q = 0; q < 4; ++q) {
            f32x2 p0 = *(const f32x2*)&gbuf[((q) * 32 + ml) * 36 + jl2];
            f32x2 p1 = *(const f32x2*)&gbuf[((4 + q) * 32 + ml) * 36 + jl2];
            gv[q] = p0 + p1;
        }

        float hN[2];
        #pragma unroll
        for (int u = 0; u < 2; ++u) {
            float gi  = gv[0][u] + g0v[0][u];
            float gf  = gv[1][u] + g0v[1][u];
            float gg_ = gv[2][u] + g0v[2][u];
            float go  = gv[3][u] + g0v[3][u];
            float si = 1.0f / (1.0f + expf(-gi));
            float sf = 1.0f / (1.0f + expf(-gf));
            float so = 1.0f / (1.0f + expf(-go));
            float tg = tanhf(gg_);
            float cN = sf * cReg[u] + si * tg;
            hN[u] = so * tanhf(cN);
            cReg[u] = cN;
        }
        size_t p = (size_t)(m0 + ml) * HID + jh;
        if (t == SEQW - 1) {
            *(f32x2*)(out + p) = (f32x2){hN[0], hN[1]};
        } else {
            unsigned int hv = (unsigned int)f16bits((_Float16)hN[0]) |
                              ((unsigned int)f16bits((_Float16)hN[1]) << 16);
            __hip_atomic_store((unsigned int*)(hOut + p), hv,
                               __ATOMIC_RELAXED, __HIP_MEMORY_SCOPE_AGENT);

            __syncthreads();   // ALL waves' h sc1-stores drained (L3-visible)
            unsigned int t1 = (unsigned int)(t + 1);
            if (tid == 0)
                __hip_atomic_store(flags + lid * 16, t1,
                                   __ATOMIC_RELAXED, __HIP_MEMORY_SCOPE_AGENT);
            if (w == 0) {
                for (;;) {
                    unsigned int v = __hip_atomic_load(
                        flags + (lane & 31) * 16, __ATOMIC_RELAXED,
                        __HIP_MEMORY_SCOPE_AGENT);
                    if (__all(v >= t1)) break;
                    __builtin_amdgcn_s_sleep(1);
                }
            }
            __syncthreads();
        }
    }
}

extern "C" void kernel_launch(void* const* d_in, const int* in_sizes, int n_in,
                              void* d_out, int out_size, void* d_ws, size_t ws_size,
                              hipStream_t stream) {
    const int*   qv   = (const int*)d_in[0];
    const float* Wemb = (const float*)d_in[2];
    const float* Wih  = (const float*)d_in[3];
    const float* Whh  = (const float*)d_in[4];
    const float* b_ih = (const float*)d_in[5];
    const float* b_hh = (const float*)d_in[6];
    float* out = (float*)d_out;

    char* ws = (char*)d_ws;
    size_t off = 0;
    unsigned short* eHi  = (unsigned short*)(ws + off); off += (size_t)MTOT * EMBD * 2;
    unsigned short* ih   = (unsigned short*)(ws + off); off += (size_t)NGATE * EMBD * 2;
    unsigned short* hh   = (unsigned short*)(ws + off); off += (size_t)NGATE * HID * 2;
    unsigned short* hBuf = (unsigned short*)(ws + off); off += (size_t)(SEQW + 1) * NB * HID * 2;
    float* bsum          = (float*)(ws + off);          off += (size_t)NGATE * 4;
    unsigned int* bar    = (unsigned int*)(ws + off);   off += 16384;
    off = (off + 255) & ~(size_t)255;
    unsigned short* G0h  = (unsigned short*)(ws + off); off += (size_t)MTOT * NGATE * 2; // 54.5 MB
    unsigned short* WembT = (unsigned short*)G0h;       // aliases G0h (dead before pregemm)

    init_kernel<<<NB * HID / 256, 256, 0, stream>>>(hBuf, bar);
    transp_kernel<<<dim3(782, 8), 256, 0, stream>>>(Wemb, WembT);
    embed_kernel<<<MTOT / 4, 256, 0, stream>>>(qv, WembT, eHi);
    convw_kernel<<<NGATE, 256, 0, stream>>>(Wih, Whh, b_ih, b_hh, ih, hh, bsum);
    pregemm_kernel<<<1664, 512, 0, stream>>>(eHi, ih, bsum, G0h);

    lstm_persist<<<256, 512, 102400, stream>>>(hh, hBuf, G0h, out, bar);
}